// Round 13
// baseline (175.456 us; speedup 1.0000x reference)
//
#include <hip/hip_runtime.h>
#include <hip/hip_bf16.h>

#define N_SEQ 4096
#define DIM   128
#define NH    4
#define DH    32
#define BATCH 4

// scale = (1/sqrt(32)) * log2(e): softmax computed in exp2 domain
#define QSCALE 0.25503495870989204f

typedef __bf16 bf16x8 __attribute__((ext_vector_type(8)));
typedef __bf16 bf16x2 __attribute__((ext_vector_type(2)));
typedef __bf16 bf16x4 __attribute__((ext_vector_type(4)));
typedef float  f32x4  __attribute__((ext_vector_type(4)));

#define MFMA(a, b, c) __builtin_amdgcn_mfma_f32_16x16x32_bf16((a), (b), (c), 0, 0, 0)

static __device__ __forceinline__ bf16x8 cvt8(const float* __restrict__ p) {
    const float4* f4 = reinterpret_cast<const float4*>(p);
    float4 a = f4[0], b = f4[1];
    bf16x8 r;
    r[0] = (__bf16)a.x; r[1] = (__bf16)a.y; r[2] = (__bf16)a.z; r[3] = (__bf16)a.w;
    r[4] = (__bf16)b.x; r[5] = (__bf16)b.y; r[6] = (__bf16)b.z; r[7] = (__bf16)b.w;
    return r;
}

static __device__ __forceinline__ f32x4 exp4(f32x4 s) {
    f32x4 r;
    r[0] = __builtin_amdgcn_exp2f(s[0]);
    r[1] = __builtin_amdgcn_exp2f(s[1]);
    r[2] = __builtin_amdgcn_exp2f(s[2]);
    r[3] = __builtin_amdgcn_exp2f(s[3]);
    return r;
}

// adjacent-pair writes -> compiler can fuse into packed bf16 converts
static __device__ __forceinline__ bf16x8 pack8(f32x4 a, f32x4 b) {
    bf16x8 o;
    o[0] = (__bf16)a[0]; o[1] = (__bf16)a[1];
    o[2] = (__bf16)a[2]; o[3] = (__bf16)a[3];
    o[4] = (__bf16)b[0]; o[5] = (__bf16)b[1];
    o[6] = (__bf16)b[2]; o[7] = (__bf16)b[3];
    return o;
}

// ---------------------------------------------------------------------------
// Kernel 1: fused QKV projection, operand-SWAPPED MFMA (A=W rows, B=x rows).
// (unchanged — held control)
// ---------------------------------------------------------------------------
__global__ __launch_bounds__(256) void proj_qkv(
    const float* __restrict__ xq, const float* __restrict__ xk, const float* __restrict__ xv,
    const float* __restrict__ Wq, const float* __restrict__ Wk, const float* __restrict__ Wv,
    const float* __restrict__ bq, const float* __restrict__ bk, const float* __restrict__ bv,
    __bf16* __restrict__ Qs, __bf16* __restrict__ Kb, __bf16* __restrict__ Vt)
{
    __shared__ __align__(16) char wlds[34816];        // 128 rows x 272 B
    const int z = blockIdx.z;
    const float* x    = (z == 0) ? xq : ((z == 1) ? xk : xv);
    const float* Wf   = (z == 0) ? Wq : ((z == 1) ? Wk : Wv);
    const float* bias = (z == 0) ? bq : ((z == 1) ? bk : bv);
    const int b    = blockIdx.y;
    const int tid  = threadIdx.x;
    const int wave = tid >> 6, lane = tid & 63;
    const int quad = lane >> 4, l15 = lane & 15;
    const int n0   = blockIdx.x * 64 + wave * 16;

    {   // stage W (fp32 -> bf16) into LDS: thread = half-row
        const int r = tid >> 1, half = tid & 1;
        const float* wsrc = Wf + r * DIM + half * 64;
        char* wdst = wlds + r * 272 + half * 128;
        #pragma unroll
        for (int i = 0; i < 8; i++)
            *(bf16x8*)(wdst + i * 16) = cvt8(wsrc + i * 8);
    }

    bf16x8 a[4];
    const float* xrow = x + (b * N_SEQ + n0 + l15) * DIM + quad * 8;
    a[0] = cvt8(xrow);      a[1] = cvt8(xrow + 32);
    a[2] = cvt8(xrow + 64); a[3] = cvt8(xrow + 96);
    __syncthreads();

    const int n = n0 + l15;                    // D col = n (swapped)
    for (int t = 0; t < 8; t++) {
        const char* wr = wlds + (t * 16 + l15) * 272 + quad * 16;
        bf16x8 w0 = *(const bf16x8*)(wr);
        bf16x8 w1 = *(const bf16x8*)(wr + 64);
        bf16x8 w2 = *(const bf16x8*)(wr + 128);
        bf16x8 w3 = *(const bf16x8*)(wr + 192);

        f32x4 acc = {0.f, 0.f, 0.f, 0.f};
        acc = MFMA(w0, a[0], acc);
        acc = MFMA(w1, a[1], acc);
        acc = MFMA(w2, a[2], acc);
        acc = MFMA(w3, a[3], acc);

        const int d0 = t * 16 + quad * 4;      // D row = d0 + r
        if (z == 0) {
            const int h = d0 >> 5, dh0 = d0 & 31;
            bf16x4 q4;
            #pragma unroll
            for (int r = 0; r < 4; r++)
                q4[r] = (__bf16)((acc[r] + bias[d0 + r]) * QSCALE);
            *(bf16x4*)(Qs + ((b * NH + h) * N_SEQ + n) * DH + dh0) = q4;
        } else if (z == 1) {
            const int h = d0 >> 5, dh0 = d0 & 31;
            bf16x4 k4;
            #pragma unroll
            for (int r = 0; r < 4; r++)
                k4[r] = (__bf16)(acc[r] + bias[d0 + r]);
            *(bf16x4*)(Kb + ((b * NH + h) * N_SEQ + n) * DH + dh0) = k4;
        } else {
            const int nl = n & 63;
            const int np = (n & ~63) | (nl & 35) | ((nl & 12) << 1) | ((nl & 16) >> 2);
            #pragma unroll
            for (int r = 0; r < 4; r++) {
                const int d = d0 + r, h = d >> 5, dh = d & 31;
                Vt[((b * NH + h) * DH + dh) * N_SEQ + np] = (__bf16)(acc[r] + bias[d]);
            }
        }
    }
}

// ---------------------------------------------------------------------------
// Kernel 2: attention — 4 blocks/CU for barrier de-phasing.
// grid = 1024 (bh=bid&15), block = 256 = 4 waves: ONE query group (64 q,
// shared qf) x 4-way split-K (wave kh handles keys kh*1024..+1024).
// SINGLE-buffered LDS (K 4x5120 + V 4x4608 = 38912 B -> exactly 4 blocks/CU,
// 4 waves/SIMD from INDEPENDENT blocks whose barriers de-phase — unlike
// R11's same-block waves that phase-locked on one barrier).
// Round (64 keys/wave): ds_read frags -> barrier -> ds_write next tiles
// (prefetched into regs at round top) + compute (reg-only) -> barrier.
// P in registers (Vt key-permuted -> score regs pack into PV B-frag).
// Split-K combine via dead K LDS region.  No online max.
// ---------------------------------------------------------------------------
__global__ __launch_bounds__(256, 4) void flash_attn(
    const __bf16* __restrict__ Qs, const __bf16* __restrict__ Kb,
    const __bf16* __restrict__ Vt, __bf16* __restrict__ ctxb)
{
    __shared__ __align__(16) char smem[38912];
    char* const Kbase = smem;                  // + kh*5120
    char* const Vbase = smem + 20480;          // + kh*4608

    const int bid  = blockIdx.x;
    const int bh   = bid & 15;                 // consecutive blocks cycle heads
    const int qc   = bid >> 4;                 // 0..63, 64 queries each
    const int tid  = threadIdx.x;
    const int kh   = tid >> 6, lane = tid & 63;
    const int quad = lane >> 4, l15 = lane & 15;
    const int n0   = qc * 64;
    const int KH   = 1024;                     // keys per kh wave

    // Q B-fragments: 4 tiles of 16 queries (same for all 4 waves)
    const __bf16* Qp = Qs + (bh * N_SEQ + n0) * DH;
    bf16x8 qf[4];
    #pragma unroll
    for (int q = 0; q < 4; q++)
        qf[q] = *(const bf16x8*)(Qp + (q * 16 + l15) * DH + quad * 8);

    // staging: 256 threads cooperatively stage all 4 kh tiles per round.
    // K tile: 64 rows x 64B (stride 80); thread -> (row tid>>2, chunk tid&3).
    // V tile: 32 rows x 128B (stride 144); thread -> (row tid>>3, chunk tid&7).
    const int r_ = tid >> 2, c_ = tid & 3;
    const __bf16* gK = Kb + (size_t)bh * N_SEQ * DH + r_ * DH + c_ * 8;
    const __bf16* gV = Vt + ((size_t)bh * DH + (tid >> 3)) * N_SEQ + (tid & 7) * 8;
    const int kofsK = r_ * 80 + c_ * 16;
    const int kofsV = (tid >> 3) * 144 + (tid & 7) * 16;

    {   // prologue: stage round-0 tiles of all 4 kh groups
        #pragma unroll
        for (int g = 0; g < 4; g++) {
            bf16x8 kr = *(const bf16x8*)(gK + (size_t)(g * KH) * DH);
            bf16x8 vr = *(const bf16x8*)(gV + g * KH);
            *(bf16x8*)(Kbase + g * 5120 + kofsK) = kr;
            *(bf16x8*)(Vbase + g * 4608 + kofsV) = vr;
        }
    }
    __syncthreads();

    char* const Kme = Kbase + kh * 5120;
    char* const Vme = Vbase + kh * 4608;

    f32x4 c[4][2];
    #pragma unroll
    for (int q = 0; q < 4; q++) { c[q][0] = f32x4{0.f,0.f,0.f,0.f}; c[q][1] = f32x4{0.f,0.f,0.f,0.f}; }
    f32x4 lv[4];
    #pragma unroll
    for (int q = 0; q < 4; q++) lv[q] = f32x4{0.f,0.f,0.f,0.f};
    const f32x4 z4 = {0.f,0.f,0.f,0.f};

    for (int kb = 0; kb < KH / 64; kb++) {     // 16 rounds
        // prefetch next round's tiles for all kh groups (wraps; harmless)
        const int kn = (kb + 1) & (KH / 64 - 1);
        bf16x8 krn[4], vrn[4];
        #pragma unroll
        for (int g = 0; g < 4; g++) {
            krn[g] = *(const bf16x8*)(gK + (size_t)(g * KH + kn * 64) * DH);
            vrn[g] = *(const bf16x8*)(gV + g * KH + kn * 64);
        }

        // read my kh tile's fragments into regs
        bf16x8 kf0 = *(const bf16x8*)(Kme + l15 * 80 + quad * 16);
        bf16x8 kf1 = *(const bf16x8*)(Kme + (16 + l15) * 80 + quad * 16);
        bf16x8 kf2 = *(const bf16x8*)(Kme + (32 + l15) * 80 + quad * 16);
        bf16x8 kf3 = *(const bf16x8*)(Kme + (48 + l15) * 80 + quad * 16);
        bf16x8 vf00 = *(const bf16x8*)(Vme + l15 * 144 + quad * 16);          // d0-15,  g0
        bf16x8 vf10 = *(const bf16x8*)(Vme + (16 + l15) * 144 + quad * 16);   // d16-31, g0
        bf16x8 vf01 = *(const bf16x8*)(Vme + l15 * 144 + 64 + quad * 16);     // d0-15,  g1
        bf16x8 vf11 = *(const bf16x8*)(Vme + (16 + l15) * 144 + 64 + quad * 16);

        __syncthreads();                       // all reads done -> safe to overwrite

        // stage next round's tiles (fire-and-forget; overlaps compute below)
        #pragma unroll
        for (int g = 0; g < 4; g++) {
            *(bf16x8*)(Kbase + g * 5120 + kofsK) = krn[g];
            *(bf16x8*)(Vbase + g * 4608 + kofsV) = vrn[g];
        }

        // compute (registers only): scores -> exp2 -> P -> PV
        bf16x8 pf[4][2];
        #pragma unroll
        for (int q = 0; q < 4; q++) {
            f32x4 sa = MFMA(kf0, qf[q], z4);
            f32x4 sb = MFMA(kf1, qf[q], z4);
            f32x4 sc = MFMA(kf2, qf[q], z4);
            f32x4 sd = MFMA(kf3, qf[q], z4);
            f32x4 ea = exp4(sa), eb = exp4(sb), ec = exp4(sc), ed = exp4(sd);
            lv[q] += (ea + eb) + (ec + ed);    // vector partials; horizontal at end
            pf[q][0] = pack8(ea, eb);          // keys g0
            pf[q][1] = pack8(ec, ed);          // keys g1
        }

        #pragma unroll
        for (int q = 0; q < 4; q++) {
            c[q][0] = MFMA(vf00, pf[q][0], c[q][0]);
            c[q][1] = MFMA(vf10, pf[q][0], c[q][1]);
            c[q][0] = MFMA(vf01, pf[q][1], c[q][0]);
            c[q][1] = MFMA(vf11, pf[q][1], c[q][1]);
        }

        __syncthreads();                       // staged tiles visible
    }

    // l: horizontal sum of vector partials, then reduce over quads
    float l[4];
    #pragma unroll
    for (int q = 0; q < 4; q++) {
        l[q] = (lv[q][0] + lv[q][1]) + (lv[q][2] + lv[q][3]);
        l[q] += __shfl_xor(l[q], 16);
        l[q] += __shfl_xor(l[q], 32);
    }

    // split-K combine via dead K/V LDS (3 partial waves x 64 lanes x 144 B)
    if (kh != 0) {
        char* dst = smem + ((kh - 1) * 64 + lane) * 144;
        #pragma unroll
        for (int q = 0; q < 4; q++) {
            *(f32x4*)(dst + (q * 2 + 0) * 16) = c[q][0];
            *(f32x4*)(dst + (q * 2 + 1) * 16) = c[q][1];
        }
        f32x4 lw = {l[0], l[1], l[2], l[3]};
        *(f32x4*)(dst + 128) = lw;
    }
    __syncthreads();
    if (kh == 0) {
        #pragma unroll
        for (int m = 0; m < 3; m++) {
            const char* src = smem + (m * 64 + lane) * 144;
            #pragma unroll
            for (int q = 0; q < 4; q++) {
                c[q][0] += *(const f32x4*)(src + (q * 2 + 0) * 16);
                c[q][1] += *(const f32x4*)(src + (q * 2 + 1) * 16);
            }
            f32x4 lp = *(const f32x4*)(src + 128);
            l[0] += lp[0]; l[1] += lp[1]; l[2] += lp[2]; l[3] += lp[3];
        }
        const int b = bh >> 2, h = bh & 3;
        #pragma unroll
        for (int q = 0; q < 4; q++) {
            const float inv = 1.0f / l[q];
            const int qg = n0 + q * 16 + l15;
            __bf16* dst = ctxb + ((size_t)(b * N_SEQ + qg)) * DIM + h * DH + quad * 4;
            #pragma unroll
            for (int dt = 0; dt < 2; dt++) {
                f32x4 cc = c[q][dt];
                bf16x2 e0 = {(__bf16)(cc[0] * inv), (__bf16)(cc[1] * inv)};
                bf16x2 e1 = {(__bf16)(cc[2] * inv), (__bf16)(cc[3] * inv)};
                *(bf16x2*)(dst + dt * 16)     = e0;
                *(bf16x2*)(dst + dt * 16 + 2) = e1;
            }
        }
    }
}

// ---------------------------------------------------------------------------
// Kernel 3: output projection, operand-swapped + Wo staged in LDS.
// (unchanged — held control)
// ---------------------------------------------------------------------------
__global__ __launch_bounds__(256) void out_proj(
    const __bf16* __restrict__ ctxb, const float* __restrict__ Wo,
    const float* __restrict__ bo, float* __restrict__ out)
{
    __shared__ __align__(16) char wlds[34816];
    const int b    = blockIdx.y;
    const int tid  = threadIdx.x;
    const int wave = tid >> 6, lane = tid & 63;
    const int quad = lane >> 4, l15 = lane & 15;
    const int n0   = blockIdx.x * 64 + wave * 16;

    {   // stage Wo (fp32 -> bf16) into LDS
        const int r = tid >> 1, half = tid & 1;
        const float* wsrc = Wo + r * DIM + half * 64;
        char* wdst = wlds + r * 272 + half * 128;
        #pragma unroll
        for (int i = 0; i < 8; i++)
            *(bf16x8*)(wdst + i * 16) = cvt8(wsrc + i * 8);
    }

    bf16x8 a[4];
    const __bf16* crow = ctxb + (b * N_SEQ + n0 + l15) * DIM + quad * 8;
    a[0] = *(const bf16x8*)(crow);
    a[1] = *(const bf16x8*)(crow + 32);
    a[2] = *(const bf16x8*)(crow + 64);
    a[3] = *(const bf16x8*)(crow + 96);
    __syncthreads();

    const int n = n0 + l15;
    for (int t = 0; t < 8; t++) {
        const char* wr = wlds + (t * 16 + l15) * 272 + quad * 16;
        bf16x8 w0 = *(const bf16x8*)(wr);
        bf16x8 w1 = *(const bf16x8*)(wr + 64);
        bf16x8 w2 = *(const bf16x8*)(wr + 128);
        bf16x8 w3 = *(const bf16x8*)(wr + 192);

        f32x4 acc = {0.f, 0.f, 0.f, 0.f};
        acc = MFMA(w0, a[0], acc);
        acc = MFMA(w1, a[1], acc);
        acc = MFMA(w2, a[2], acc);
        acc = MFMA(w3, a[3], acc);

        const int d0 = t * 16 + quad * 4;
        float4 o;
        o.x = acc[0] + bo[d0];
        o.y = acc[1] + bo[d0 + 1];
        o.z = acc[2] + bo[d0 + 2];
        o.w = acc[3] + bo[d0 + 3];
        *(float4*)(out + (b * N_SEQ + n) * DIM + d0) = o;
    }
}

// ---------------------------------------------------------------------------
extern "C" void kernel_launch(void* const* d_in, const int* in_sizes, int n_in,
                              void* d_out, int out_size, void* d_ws, size_t ws_size,
                              hipStream_t stream)
{
    const float* query = (const float*)d_in[0];
    const float* key   = (const float*)d_in[1];
    const float* value = (const float*)d_in[2];
    const float* Wq = (const float*)d_in[3];
    const float* bq = (const float*)d_in[4];
    const float* Wk = (const float*)d_in[5];
    const float* bk = (const float*)d_in[6];
    const float* Wv = (const float*)d_in[7];
    const float* bv = (const float*)d_in[8];
    const float* Wo = (const float*)d_in[9];
    const float* bo = (const float*)d_in[10];
    float* out = (float*)d_out;

    char* ws = (char*)d_ws;
    const size_t e = (size_t)BATCH * N_SEQ * DIM;   // 2,097,152 elements
    __bf16* Qs   = (__bf16*)(ws);                   // 4 MB  [B,H,N,32] scaled
    __bf16* Kb   = (__bf16*)(ws + 2 * e);           // 4 MB  [B,H,N,32] identity
    __bf16* Vt   = (__bf16*)(ws + 4 * e);           // 4 MB  [B,H,32,N] key-permuted
    __bf16* ctxb = (__bf16*)(ws + 6 * e);           // 4 MB  [B,N,128]

    proj_qkv<<<dim3(64, BATCH, 3), 256, 0, stream>>>(
        query, key, value, Wq, Wk, Wv, bq, bk, bv, Qs, Kb, Vt);
    flash_attn<<<dim3(1024), 256, 0, stream>>>(Qs, Kb, Vt, ctxb);
    out_proj<<<dim3(64, BATCH), 256, 0, stream>>>(ctxb, Wo, bo, out);
}

// Round 14
// 155.449 us; speedup vs baseline: 1.1287x; 1.1287x over previous
//
#include <hip/hip_runtime.h>
#include <hip/hip_bf16.h>

#define N_SEQ 4096
#define DIM   128
#define NH    4
#define DH    32
#define BATCH 4

// scale = (1/sqrt(32)) * log2(e): softmax computed in exp2 domain
#define QSCALE 0.25503495870989204f

typedef __bf16 bf16x8 __attribute__((ext_vector_type(8)));
typedef __bf16 bf16x2 __attribute__((ext_vector_type(2)));
typedef __bf16 bf16x4 __attribute__((ext_vector_type(4)));
typedef float  f32x4  __attribute__((ext_vector_type(4)));

#define MFMA(a, b, c) __builtin_amdgcn_mfma_f32_16x16x32_bf16((a), (b), (c), 0, 0, 0)

static __device__ __forceinline__ bf16x8 cvt8(const float* __restrict__ p) {
    const float4* f4 = reinterpret_cast<const float4*>(p);
    float4 a = f4[0], b = f4[1];
    bf16x8 r;
    r[0] = (__bf16)a.x; r[1] = (__bf16)a.y; r[2] = (__bf16)a.z; r[3] = (__bf16)a.w;
    r[4] = (__bf16)b.x; r[5] = (__bf16)b.y; r[6] = (__bf16)b.z; r[7] = (__bf16)b.w;
    return r;
}

static __device__ __forceinline__ f32x4 exp4(f32x4 s) {
    f32x4 r;
    r[0] = __builtin_amdgcn_exp2f(s[0]);
    r[1] = __builtin_amdgcn_exp2f(s[1]);
    r[2] = __builtin_amdgcn_exp2f(s[2]);
    r[3] = __builtin_amdgcn_exp2f(s[3]);
    return r;
}

// adjacent-pair writes -> compiler can fuse into packed bf16 converts
static __device__ __forceinline__ bf16x8 pack8(f32x4 a, f32x4 b) {
    bf16x8 o;
    o[0] = (__bf16)a[0]; o[1] = (__bf16)a[1];
    o[2] = (__bf16)a[2]; o[3] = (__bf16)a[3];
    o[4] = (__bf16)b[0]; o[5] = (__bf16)b[1];
    o[6] = (__bf16)b[2]; o[7] = (__bf16)b[3];
    return o;
}

// ---------------------------------------------------------------------------
// Kernel 1: fused QKV projection, operand-SWAPPED MFMA (A=W rows, B=x rows).
// (unchanged — held control)
// ---------------------------------------------------------------------------
__global__ __launch_bounds__(256) void proj_qkv(
    const float* __restrict__ xq, const float* __restrict__ xk, const float* __restrict__ xv,
    const float* __restrict__ Wq, const float* __restrict__ Wk, const float* __restrict__ Wv,
    const float* __restrict__ bq, const float* __restrict__ bk, const float* __restrict__ bv,
    __bf16* __restrict__ Qs, __bf16* __restrict__ Kb, __bf16* __restrict__ Vt)
{
    __shared__ __align__(16) char wlds[34816];        // 128 rows x 272 B
    const int z = blockIdx.z;
    const float* x    = (z == 0) ? xq : ((z == 1) ? xk : xv);
    const float* Wf   = (z == 0) ? Wq : ((z == 1) ? Wk : Wv);
    const float* bias = (z == 0) ? bq : ((z == 1) ? bk : bv);
    const int b    = blockIdx.y;
    const int tid  = threadIdx.x;
    const int wave = tid >> 6, lane = tid & 63;
    const int quad = lane >> 4, l15 = lane & 15;
    const int n0   = blockIdx.x * 64 + wave * 16;

    {   // stage W (fp32 -> bf16) into LDS: thread = half-row
        const int r = tid >> 1, half = tid & 1;
        const float* wsrc = Wf + r * DIM + half * 64;
        char* wdst = wlds + r * 272 + half * 128;
        #pragma unroll
        for (int i = 0; i < 8; i++)
            *(bf16x8*)(wdst + i * 16) = cvt8(wsrc + i * 8);
    }

    bf16x8 a[4];
    const float* xrow = x + (b * N_SEQ + n0 + l15) * DIM + quad * 8;
    a[0] = cvt8(xrow);      a[1] = cvt8(xrow + 32);
    a[2] = cvt8(xrow + 64); a[3] = cvt8(xrow + 96);
    __syncthreads();

    const int n = n0 + l15;                    // D col = n (swapped)
    for (int t = 0; t < 8; t++) {
        const char* wr = wlds + (t * 16 + l15) * 272 + quad * 16;
        bf16x8 w0 = *(const bf16x8*)(wr);
        bf16x8 w1 = *(const bf16x8*)(wr + 64);
        bf16x8 w2 = *(const bf16x8*)(wr + 128);
        bf16x8 w3 = *(const bf16x8*)(wr + 192);

        f32x4 acc = {0.f, 0.f, 0.f, 0.f};
        acc = MFMA(w0, a[0], acc);
        acc = MFMA(w1, a[1], acc);
        acc = MFMA(w2, a[2], acc);
        acc = MFMA(w3, a[3], acc);

        const int d0 = t * 16 + quad * 4;      // D row = d0 + r
        if (z == 0) {
            const int h = d0 >> 5, dh0 = d0 & 31;
            bf16x4 q4;
            #pragma unroll
            for (int r = 0; r < 4; r++)
                q4[r] = (__bf16)((acc[r] + bias[d0 + r]) * QSCALE);
            *(bf16x4*)(Qs + ((b * NH + h) * N_SEQ + n) * DH + dh0) = q4;
        } else if (z == 1) {
            const int h = d0 >> 5, dh0 = d0 & 31;
            bf16x4 k4;
            #pragma unroll
            for (int r = 0; r < 4; r++)
                k4[r] = (__bf16)(acc[r] + bias[d0 + r]);
            *(bf16x4*)(Kb + ((b * NH + h) * N_SEQ + n) * DH + dh0) = k4;
        } else {
            const int nl = n & 63;
            const int np = (n & ~63) | (nl & 35) | ((nl & 12) << 1) | ((nl & 16) >> 2);
            #pragma unroll
            for (int r = 0; r < 4; r++) {
                const int d = d0 + r, h = d >> 5, dh = d & 31;
                Vt[((b * NH + h) * DH + dh) * N_SEQ + np] = (__bf16)(acc[r] + bias[d]);
            }
        }
    }
}

// ---------------------------------------------------------------------------
// Kernel 2: attention — R13 structure with the spill fixed:
// __launch_bounds__(256,2) (cap 256).  R13's (256,4) cap=128 forced VGPR=64
// + scratch spill (FETCH 17MB/WRITE 28MB).  Natural allocation ~140-180 ->
// HW occupancy = min(LDS 38.9KB -> 4 blocks/CU, VGPR -> ~3/SIMD) = 3
// independent blocks/CU whose barriers de-phase (the R11 phase-lock fix).
// Also shrunk prefetch footprint: only K prefetched into regs across the
// compute phase; V re-read from global (L2-hot) right at the store phase.
// grid = 1024 (bh=bid&15), block = 256 = 4 waves: 1 query group (64 q,
// shared qf) x 4-way split-K.  Single-buffered LDS, 2 barriers/round.
// P in registers (Vt key-permuted -> score regs pack into PV B-frag).
// Split-K combine via dead LDS.  No online max.
// ---------------------------------------------------------------------------
__global__ __launch_bounds__(256, 2) void flash_attn(
    const __bf16* __restrict__ Qs, const __bf16* __restrict__ Kb,
    const __bf16* __restrict__ Vt, __bf16* __restrict__ ctxb)
{
    __shared__ __align__(16) char smem[38912];
    char* const Kbase = smem;                  // + kh*5120
    char* const Vbase = smem + 20480;          // + kh*4608

    const int bid  = blockIdx.x;
    const int bh   = bid & 15;                 // consecutive blocks cycle heads
    const int qc   = bid >> 4;                 // 0..63, 64 queries each
    const int tid  = threadIdx.x;
    const int kh   = tid >> 6, lane = tid & 63;
    const int quad = lane >> 4, l15 = lane & 15;
    const int n0   = qc * 64;
    const int KH   = 1024;                     // keys per kh wave

    // Q B-fragments: 4 tiles of 16 queries (same for all 4 waves)
    const __bf16* Qp = Qs + (bh * N_SEQ + n0) * DH;
    bf16x8 qf[4];
    #pragma unroll
    for (int q = 0; q < 4; q++)
        qf[q] = *(const bf16x8*)(Qp + (q * 16 + l15) * DH + quad * 8);

    // staging: 256 threads cooperatively stage all 4 kh tiles per round.
    const int r_ = tid >> 2, c_ = tid & 3;
    const __bf16* gK = Kb + (size_t)bh * N_SEQ * DH + r_ * DH + c_ * 8;
    const __bf16* gV = Vt + ((size_t)bh * DH + (tid >> 3)) * N_SEQ + (tid & 7) * 8;
    const int kofsK = r_ * 80 + c_ * 16;
    const int kofsV = (tid >> 3) * 144 + (tid & 7) * 16;

    {   // prologue: stage round-0 tiles of all 4 kh groups
        #pragma unroll
        for (int g = 0; g < 4; g++) {
            bf16x8 kr = *(const bf16x8*)(gK + (size_t)(g * KH) * DH);
            bf16x8 vr = *(const bf16x8*)(gV + g * KH);
            *(bf16x8*)(Kbase + g * 5120 + kofsK) = kr;
            *(bf16x8*)(Vbase + g * 4608 + kofsV) = vr;
        }
    }
    __syncthreads();

    char* const Kme = Kbase + kh * 5120;
    char* const Vme = Vbase + kh * 4608;

    f32x4 c[4][2];
    #pragma unroll
    for (int q = 0; q < 4; q++) { c[q][0] = f32x4{0.f,0.f,0.f,0.f}; c[q][1] = f32x4{0.f,0.f,0.f,0.f}; }
    f32x4 lv[4];
    #pragma unroll
    for (int q = 0; q < 4; q++) lv[q] = f32x4{0.f,0.f,0.f,0.f};
    const f32x4 z4 = {0.f,0.f,0.f,0.f};

    for (int kb = 0; kb < KH / 64; kb++) {     // 16 rounds
        const int kn = (kb + 1) & (KH / 64 - 1);

        // prefetch next round's K tiles into regs (issued early, used late)
        bf16x8 krn[4];
        #pragma unroll
        for (int g = 0; g < 4; g++)
            krn[g] = *(const bf16x8*)(gK + (size_t)(g * KH + kn * 64) * DH);

        // read my kh tile's fragments into regs
        bf16x8 kf0 = *(const bf16x8*)(Kme + l15 * 80 + quad * 16);
        bf16x8 kf1 = *(const bf16x8*)(Kme + (16 + l15) * 80 + quad * 16);
        bf16x8 kf2 = *(const bf16x8*)(Kme + (32 + l15) * 80 + quad * 16);
        bf16x8 kf3 = *(const bf16x8*)(Kme + (48 + l15) * 80 + quad * 16);
        bf16x8 vf00 = *(const bf16x8*)(Vme + l15 * 144 + quad * 16);          // d0-15,  g0
        bf16x8 vf10 = *(const bf16x8*)(Vme + (16 + l15) * 144 + quad * 16);   // d16-31, g0
        bf16x8 vf01 = *(const bf16x8*)(Vme + l15 * 144 + 64 + quad * 16);     // d0-15,  g1
        bf16x8 vf11 = *(const bf16x8*)(Vme + (16 + l15) * 144 + 64 + quad * 16);

        __syncthreads();                       // all reads done -> safe to overwrite

        // compute (registers only): scores -> exp2 -> P -> PV
        bf16x8 pf[4][2];
        #pragma unroll
        for (int q = 0; q < 4; q++) {
            f32x4 sa = MFMA(kf0, qf[q], z4);
            f32x4 sb = MFMA(kf1, qf[q], z4);
            f32x4 sc = MFMA(kf2, qf[q], z4);
            f32x4 sd = MFMA(kf3, qf[q], z4);
            f32x4 ea = exp4(sa), eb = exp4(sb), ec = exp4(sc), ed = exp4(sd);
            lv[q] += (ea + eb) + (ec + ed);    // vector partials; horizontal at end
            pf[q][0] = pack8(ea, eb);          // keys g0
            pf[q][1] = pack8(ec, ed);          // keys g1
        }

        #pragma unroll
        for (int q = 0; q < 4; q++) {
            c[q][0] = MFMA(vf00, pf[q][0], c[q][0]);
            c[q][1] = MFMA(vf10, pf[q][0], c[q][1]);
            c[q][0] = MFMA(vf01, pf[q][1], c[q][0]);
            c[q][1] = MFMA(vf11, pf[q][1], c[q][1]);
        }

        // stage next round's tiles: K from prefetch regs, V re-read (L2-hot)
        #pragma unroll
        for (int g = 0; g < 4; g++) {
            *(bf16x8*)(Kbase + g * 5120 + kofsK) = krn[g];
            bf16x8 vr = *(const bf16x8*)(gV + g * KH + kn * 64);
            *(bf16x8*)(Vbase + g * 4608 + kofsV) = vr;
        }
        __syncthreads();                       // staged tiles visible
    }

    // l: horizontal sum of vector partials, then reduce over quads
    float l[4];
    #pragma unroll
    for (int q = 0; q < 4; q++) {
        l[q] = (lv[q][0] + lv[q][1]) + (lv[q][2] + lv[q][3]);
        l[q] += __shfl_xor(l[q], 16);
        l[q] += __shfl_xor(l[q], 32);
    }

    // split-K combine via dead K/V LDS (3 partial waves x 64 lanes x 144 B)
    if (kh != 0) {
        char* dst = smem + ((kh - 1) * 64 + lane) * 144;
        #pragma unroll
        for (int q = 0; q < 4; q++) {
            *(f32x4*)(dst + (q * 2 + 0) * 16) = c[q][0];
            *(f32x4*)(dst + (q * 2 + 1) * 16) = c[q][1];
        }
        f32x4 lw = {l[0], l[1], l[2], l[3]};
        *(f32x4*)(dst + 128) = lw;
    }
    __syncthreads();
    if (kh == 0) {
        #pragma unroll
        for (int m = 0; m < 3; m++) {
            const char* src = smem + (m * 64 + lane) * 144;
            #pragma unroll
            for (int q = 0; q < 4; q++) {
                c[q][0] += *(const f32x4*)(src + (q * 2 + 0) * 16);
                c[q][1] += *(const f32x4*)(src + (q * 2 + 1) * 16);
            }
            f32x4 lp = *(const f32x4*)(src + 128);
            l[0] += lp[0]; l[1] += lp[1]; l[2] += lp[2]; l[3] += lp[3];
        }
        const int b = bh >> 2, h = bh & 3;
        #pragma unroll
        for (int q = 0; q < 4; q++) {
            const float inv = 1.0f / l[q];
            const int qg = n0 + q * 16 + l15;
            __bf16* dst = ctxb + ((size_t)(b * N_SEQ + qg)) * DIM + h * DH + quad * 4;
            #pragma unroll
            for (int dt = 0; dt < 2; dt++) {
                f32x4 cc = c[q][dt];
                bf16x2 e0 = {(__bf16)(cc[0] * inv), (__bf16)(cc[1] * inv)};
                bf16x2 e1 = {(__bf16)(cc[2] * inv), (__bf16)(cc[3] * inv)};
                *(bf16x2*)(dst + dt * 16)     = e0;
                *(bf16x2*)(dst + dt * 16 + 2) = e1;
            }
        }
    }
}

// ---------------------------------------------------------------------------
// Kernel 3: output projection, operand-swapped + Wo staged in LDS.
// (unchanged — held control)
// ---------------------------------------------------------------------------
__global__ __launch_bounds__(256) void out_proj(
    const __bf16* __restrict__ ctxb, const float* __restrict__ Wo,
    const float* __restrict__ bo, float* __restrict__ out)
{
    __shared__ __align__(16) char wlds[34816];
    const int b    = blockIdx.y;
    const int tid  = threadIdx.x;
    const int wave = tid >> 6, lane = tid & 63;
    const int quad = lane >> 4, l15 = lane & 15;
    const int n0   = blockIdx.x * 64 + wave * 16;

    {   // stage Wo (fp32 -> bf16) into LDS
        const int r = tid >> 1, half = tid & 1;
        const float* wsrc = Wo + r * DIM + half * 64;
        char* wdst = wlds + r * 272 + half * 128;
        #pragma unroll
        for (int i = 0; i < 8; i++)
            *(bf16x8*)(wdst + i * 16) = cvt8(wsrc + i * 8);
    }

    bf16x8 a[4];
    const __bf16* crow = ctxb + (b * N_SEQ + n0 + l15) * DIM + quad * 8;
    a[0] = *(const bf16x8*)(crow);
    a[1] = *(const bf16x8*)(crow + 32);
    a[2] = *(const bf16x8*)(crow + 64);
    a[3] = *(const bf16x8*)(crow + 96);
    __syncthreads();

    const int n = n0 + l15;
    for (int t = 0; t < 8; t++) {
        const char* wr = wlds + (t * 16 + l15) * 272 + quad * 16;
        bf16x8 w0 = *(const bf16x8*)(wr);
        bf16x8 w1 = *(const bf16x8*)(wr + 64);
        bf16x8 w2 = *(const bf16x8*)(wr + 128);
        bf16x8 w3 = *(const bf16x8*)(wr + 192);

        f32x4 acc = {0.f, 0.f, 0.f, 0.f};
        acc = MFMA(w0, a[0], acc);
        acc = MFMA(w1, a[1], acc);
        acc = MFMA(w2, a[2], acc);
        acc = MFMA(w3, a[3], acc);

        const int d0 = t * 16 + quad * 4;
        float4 o;
        o.x = acc[0] + bo[d0];
        o.y = acc[1] + bo[d0 + 1];
        o.z = acc[2] + bo[d0 + 2];
        o.w = acc[3] + bo[d0 + 3];
        *(float4*)(out + (b * N_SEQ + n) * DIM + d0) = o;
    }
}

// ---------------------------------------------------------------------------
extern "C" void kernel_launch(void* const* d_in, const int* in_sizes, int n_in,
                              void* d_out, int out_size, void* d_ws, size_t ws_size,
                              hipStream_t stream)
{
    const float* query = (const float*)d_in[0];
    const float* key   = (const float*)d_in[1];
    const float* value = (const float*)d_in[2];
    const float* Wq = (const float*)d_in[3];
    const float* bq = (const float*)d_in[4];
    const float* Wk = (const float*)d_in[5];
    const float* bk = (const float*)d_in[6];
    const float* Wv = (const float*)d_in[7];
    const float* bv = (const float*)d_in[8];
    const float* Wo = (const float*)d_in[9];
    const float* bo = (const float*)d_in[10];
    float* out = (float*)d_out;

    char* ws = (char*)d_ws;
    const size_t e = (size_t)BATCH * N_SEQ * DIM;   // 2,097,152 elements
    __bf16* Qs   = (__bf16*)(ws);                   // 4 MB  [B,H,N,32] scaled
    __bf16* Kb   = (__bf16*)(ws + 2 * e);           // 4 MB  [B,H,N,32] identity
    __bf16* Vt   = (__bf16*)(ws + 4 * e);           // 4 MB  [B,H,32,N] key-permuted
    __bf16* ctxb = (__bf16*)(ws + 6 * e);           // 4 MB  [B,N,128]

    proj_qkv<<<dim3(64, BATCH, 3), 256, 0, stream>>>(
        query, key, value, Wq, Wk, Wv, bq, bk, bv, Qs, Kb, Vt);
    flash_attn<<<dim3(1024), 256, 0, stream>>>(Qs, Kb, Vt, ctxb);
    out_proj<<<dim3(64, BATCH), 256, 0, stream>>>(ctxb, Wo, bo, out);
}